// Round 24
// baseline (238.168 us; speedup 1.0000x reference)
//
#include <hip/hip_runtime.h>

#define NN 50000
#define NN_PAD 50048                    // 64-aligned, covers last k_mm tile
#define NE 800000
#define DIM 64
#define TL 4
#define ET 3
#define MH 6
#define NDCAP 48                        // per-node bucket capacity (deg ~Poisson(16), P(>48)~1e-12)
#define SC_CHUNK 2048                   // edges per block slice
#define SC_SLICES ((NE + SC_CHUNK - 1) / SC_CHUNK)   // 391
#define RCAP 116384                     // per-range partition capacity (NE/8 + 16384)
#define ZROW NN                         // zero row index in bf16 planes
#define PAD_ENTRY ((unsigned)ZROW | 0x00300000u)   // srcn=ZROW (zeros), typ=3, hop=0

typedef __attribute__((ext_vector_type(8))) short short8;
typedef __attribute__((ext_vector_type(4))) float f32x4;
typedef __attribute__((ext_vector_type(2))) float f32x2;

__device__ __forceinline__ unsigned bf16rne(float f) {
    unsigned b = __float_as_uint(f);
    return (b + 0x7FFFu + ((b >> 16) & 1u)) >> 16;
}
__device__ __forceinline__ float bf2f(unsigned short u) {
    return __uint_as_float((unsigned)u << 16);
}
__device__ __forceinline__ float bf2f_lo(unsigned u) {
    return __uint_as_float(u << 16);
}
__device__ __forceinline__ float bf2f_hi(unsigned u) {
    return __uint_as_float(u & 0xFFFF0000u);
}
__device__ __forceinline__ f32x2 pkfma(float w, f32x2 v, f32x2 acc) {
    return __builtin_elementwise_fma((f32x2){w, w}, v, acc);  // v_pk_fma_f32
}

// ---------------- Phase A: partition edges by dst-range (one streaming pass) -------------

static __global__ __launch_bounds__(256) void k_part(
        const int* __restrict__ src, const int* __restrict__ dst,
        const int* __restrict__ typ, const int* __restrict__ hop,
        int* __restrict__ gcur, uint2* __restrict__ pe) {
    __shared__ int lcnt[8];
    __shared__ int lbase[8];
    if (threadIdx.x < 8) lcnt[threadIdx.x] = 0;
    __syncthreads();
    const int base = blockIdx.x * SC_CHUNK + threadIdx.x;
    int myr[8];
    int myrank[8];
    uint2 myw[8];
#pragma unroll
    for (int k = 0; k < 8; ++k) {
        int e = base + k * 256;
        myr[k] = -1;
        if (e < NE) {
            int d = dst[e];
            int r = d / (NN / 8);
            myr[k] = r;
            myrank[k] = atomicAdd(&lcnt[r], 1);
            myw[k] = make_uint2((unsigned)src[e] | ((unsigned)hop[e] << 16)
                                                | ((unsigned)typ[e] << 20),
                                (unsigned)d);
        }
    }
    __syncthreads();
    if (threadIdx.x < 8)
        lbase[threadIdx.x] = atomicAdd(&gcur[threadIdx.x], lcnt[threadIdx.x]);
    __syncthreads();
#pragma unroll
    for (int k = 0; k < 8; ++k) {
        if (myr[k] >= 0) {
            int r = myr[k];
            pe[(size_t)r * RCAP + lbase[r] + myrank[k]] = myw[k];
        }
    }
}

// ---------------- buf pre-fill with PAD entries ----------------

static __global__ __launch_bounds__(256) void k_fill(uint4* __restrict__ b) {
    int i = blockIdx.x * 256 + threadIdx.x;       // NN*NDCAP/4 = 600000 uint4
    if (i < NN * NDCAP / 4)
        b[i] = make_uint4(PAD_ENTRY, PAD_ENTRY, PAD_ENTRY, PAD_ENTRY);
}

// ---------------- Phase B: XCD-affine scatter, linear slots ----------------

static __global__ __launch_bounds__(256) void k_scatter(
        const int* __restrict__ gcur, const uint2* __restrict__ pe,
        int* __restrict__ cnt, unsigned int* __restrict__ buf) {
    const int r = blockIdx.x & 7;                 // XCD id under round-robin dispatch
    const int blk = blockIdx.x >> 3;
    const int n = gcur[r];
    const int i0 = blk * SC_CHUNK + threadIdx.x;
#pragma unroll
    for (int k = 0; k < 8; ++k) {
        int i = i0 + k * 256;
        if (i < n) {
            uint2 w = pe[(size_t)r * RCAP + i];
            int d = (int)w.y;
            int slot = atomicAdd(&cnt[d], 1);
            if (slot < NDCAP) buf[(size_t)d * NDCAP + slot] = w.x;
        }
    }
}

// ---------------- f32 -> bf16 plane convert (initial x only) ----------------

static __global__ void k_cvt(const float* __restrict__ in, unsigned short* __restrict__ out) {
    int i = blockIdx.x * blockDim.x + threadIdx.x;   // one float4 per thread
    if (i >= NN * DIM / 4) return;
    float4 v = ((const float4*)in)[i];
    uint2 p;
    p.x = bf16rne(v.x) | (bf16rne(v.y) << 16);
    p.y = bf16rne(v.z) | (bf16rne(v.w) << 16);
    ((uint2*)out)[i] = p;
}

// ---------------- W pre-pack, interleaved k-map: k = 4*dd + m --------------------------

static __global__ void k_pack(const float* __restrict__ W_edge, const float* __restrict__ W_t,
                              unsigned short* __restrict__ Bpack) {
    int idx = blockIdx.x * 256 + threadIdx.x;   // 65536 total
    if (idx >= 4 * 4 * 8 * 512) return;
    int j = idx & 7;
    int lane = (idx >> 3) & 63;
    int ks = (idx >> 9) & 7;
    int nt = (idx >> 12) & 3;
    int T = idx >> 14;
    int k = ks * 32 + 8 * (lane >> 4) + j;     // k within [0,256)
    int n = nt * 16 + (lane & 15);
    int m = k & 3, dd = k >> 2;
    float v;
    if (m < 3) v = W_edge[(((size_t)m * TL + T) * DIM + dd) * DIM + n];
    else if (T >= 1) v = W_t[((size_t)T * DIM + dd) * DIM + n];
    else v = 0.f;                               // T=0: hop slice contributes zero
    Bpack[idx] = (unsigned short)bf16rne(v);
}

// ---------------- Aggregation: TWO nodes per wave, deep load pipeline --------------------
// Half h owns node 2w+h; its 32 lanes cover all 64 dims (2 per lane); 1 edge/trip/node.
// __launch_bounds__(256,4): up to 128 VGPRs -> all base gathers + e4/e5 prefetch in flight.

template <int T>
static __global__ __launch_bounds__(256, 4) void k_agg(
        const int* __restrict__ cnt, const unsigned int* __restrict__ buf,
        const unsigned short* __restrict__ xb,
        const float* __restrict__ nu_edge, const float* __restrict__ nu_kt,
        const unsigned short* __restrict__ gp2, const unsigned short* __restrict__ gp3,
        const unsigned short* __restrict__ gp4,
        unsigned short* __restrict__ aAll, unsigned short* __restrict__ g2,
        unsigned short* __restrict__ g3, unsigned short* __restrict__ g4) {
    int gw = (blockIdx.x * blockDim.x + threadIdx.x) >> 6;   // wave id
    int pairbase = gw * 2;
    if (pairbase >= NN) return;
    int lane = threadIdx.x & 63;
    const int half = lane >> 5;
    const int hl = lane & 31;            // dims 2hl, 2hl+1
    const int node = pairbase + half;    // NN even -> node < NN

    // independent loads: entry chunks (e0..e5 prefetched), cnt, G planes
    const uint4* __restrict__ eb4 = (const uint4*)(buf + (size_t)node * NDCAP);
    uint4 e0 = eb4[0];
    uint4 e1 = eb4[1];
    uint4 e2 = eb4[2];
    uint4 e3 = eb4[3];
    uint4 e4 = eb4[4];
    uint4 e5 = eb4[5];
    int myc = cnt[node];

    f32x2 hp = {0.f, 0.f};
    if (T >= 1) {
        const float nk2 = nu_kt[T * MH + 2];
        unsigned p2 = *(const unsigned*)(gp2 + (size_t)node * DIM + 2 * hl);
        hp = pkfma(nk2, (f32x2){bf2f_lo(p2), bf2f_hi(p2)}, hp);
        if (T >= 2) {
            const float nk3 = nu_kt[T * MH + 3];
            unsigned p3 = *(const unsigned*)(gp3 + (size_t)node * DIM + 2 * hl);
            hp = pkfma(nk3, (f32x2){bf2f_lo(p3), bf2f_hi(p3)}, hp);
        }
        if (T >= 3) {
            const float nk4 = nu_kt[T * MH + 4];
            unsigned p4 = *(const unsigned*)(gp4 + (size_t)node * DIM + 2 * hl);
            hp = pkfma(nk4, (f32x2){bf2f_lo(p4), bf2f_hi(p4)}, hp);
        }
    }

    int c0 = __builtin_amdgcn_readlane(myc, 0);
    int c1 = __builtin_amdgcn_readlane(myc, 32);
    const int ntmax = min(max(c0, c1), NDCAP);   // uniform trip count

    f32x2 st = {0.f, 0.f};
    f32x2 s1 = {0.f, 0.f};
    f32x2 s2 = {0.f, 0.f};
    f32x2 a2 = {0.f, 0.f};
    f32x2 a3 = {0.f, 0.f};
    f32x2 a4 = {0.f, 0.f};

#define TRIPE(E)                                                                 \
    {                                                                            \
        unsigned sp = (E);                                                       \
        int srcn = (int)(sp & 0xFFFFu);                                          \
        unsigned pk = *(const unsigned*)(xb + (size_t)srcn * DIM + 2 * hl);      \
        f32x2 v = {bf2f_lo(pk), bf2f_hi(pk)};                                    \
        st = st + v;                       /* unflagged: pads are zero */        \
        unsigned tf = (sp >> 20) & 3u;                                           \
        s1 = pkfma((tf == 1u) ? 1.f : 0.f, v, s1);                               \
        s2 = pkfma((tf == 2u) ? 1.f : 0.f, v, s2);                               \
        if (T <= 2) {                                                            \
            unsigned hf = (sp >> 16) & 15u;                                      \
            a2 = pkfma((hf == 2u) ? 1.f : 0.f, v, a2);                           \
            if (T <= 1) a3 = pkfma((hf == 3u) ? 1.f : 0.f, v, a3);               \
            if (T == 0) a4 = pkfma((hf == 4u) ? 1.f : 0.f, v, a4);               \
        }                                                                        \
    }

    // unconditional 16 trips (covers ntmax <= 16; pads harmless)
    TRIPE(e0.x) TRIPE(e0.y) TRIPE(e0.z) TRIPE(e0.w)
    TRIPE(e1.x) TRIPE(e1.y) TRIPE(e1.z) TRIPE(e1.w)
    TRIPE(e2.x) TRIPE(e2.y) TRIPE(e2.z) TRIPE(e2.w)
    TRIPE(e3.x) TRIPE(e3.y) TRIPE(e3.z) TRIPE(e3.w)
    if (ntmax > 16) {                    // ~47% of waves; entries already in registers
        TRIPE(e4.x) TRIPE(e4.y) TRIPE(e4.z) TRIPE(e4.w)
        TRIPE(e5.x) TRIPE(e5.y) TRIPE(e5.z) TRIPE(e5.w)
        if (ntmax > 24) {                // ~4%: generic buf tail
            for (int p = 24; p < ntmax; ++p)
                TRIPE(buf[(size_t)node * NDCAP + p])
        }
    }
#undef TRIPE

    f32x2 s0 = st - s1 - s2;             // no cross-half reduction needed

    {
        float nu0 = nu_edge[0 * TL + T];
        float nu1 = nu_edge[1 * TL + T];
        float nu2 = nu_edge[2 * TL + T];
        uint4 pk;   // packed A row [node][d*4+m] for d = 2hl, 2hl+1
        pk.x = bf16rne(nu0 * s0.x) | (bf16rne(nu1 * s1.x) << 16);
        pk.y = bf16rne(nu2 * s2.x) | (bf16rne(hp.x) << 16);
        pk.z = bf16rne(nu0 * s0.y) | (bf16rne(nu1 * s1.y) << 16);
        pk.w = bf16rne(nu2 * s2.y) | (bf16rne(hp.y) << 16);
        *(uint4*)(aAll + (size_t)node * 256 + hl * 8) = pk;
        const size_t go = (size_t)node * DIM + 2 * hl;
        if (T <= 2) *(unsigned*)(g2 + go) = bf16rne(a2.x) | (bf16rne(a2.y) << 16);
        if (T <= 1) *(unsigned*)(g3 + go) = bf16rne(a3.x) | (bf16rne(a3.y) << 16);
        if (T == 0) *(unsigned*)(g4 + go) = bf16rne(a4.x) | (bf16rne(a4.y) << 16);
    }
}

// ---------------- Matmul via MFMA; bf16 residual chain; f32 out only at T=3 --------------

template <int T>
static __global__ __launch_bounds__(256) void k_mm(
        const unsigned short* __restrict__ aAll,
        const unsigned short* __restrict__ Bpack,
        const float* __restrict__ b_edge, const float* __restrict__ nu_edge,
        const float* __restrict__ b_t, const float* __restrict__ nu_kt,
        const unsigned short* __restrict__ xinb, unsigned short* __restrict__ xob,
        float* __restrict__ fout) {
    const int w = __builtin_amdgcn_readfirstlane(threadIdx.x >> 6);
    const int l = threadIdx.x & 63;
    const int g = l >> 4, i = l & 15;
    const int m0 = blockIdx.x * 64 + w * 16;

    const float nu0 = nu_edge[0 * TL + T], nu1 = nu_edge[1 * TL + T],
                nu2 = nu_edge[2 * TL + T];
    float nsum = 0.f;
    if (T >= 1) {
        nsum = nu_kt[T * MH + 2];
        if (T >= 2) nsum += nu_kt[T * MH + 3];
        if (T >= 3) nsum += nu_kt[T * MH + 4];
    }

    f32x4 acc[4];
#pragma unroll
    for (int nt = 0; nt < 4; ++nt) {
        int col = nt * 16 + i;
        float b = nu0 * b_edge[(0 * TL + T) * DIM + col]
                + nu1 * b_edge[(1 * TL + T) * DIM + col]
                + nu2 * b_edge[(2 * TL + T) * DIM + col];
        if (T >= 1) b = fmaf(nsum, b_t[T * DIM + col], b);
        acc[nt] = (f32x4){b, b, b, b};
    }

    // A: row = m0+i, k = ks*32 + 8g + [0..8)  -> one uint4 per k-step
    const uint4* __restrict__ Abase = (const uint4*)(aAll + (size_t)(m0 + i) * 256 + g * 8);
    const uint4* __restrict__ Bu = (const uint4*)Bpack;

#pragma unroll
    for (int ks = 0; ks < 8; ++ks) {
        short8 a = __builtin_bit_cast(short8, Abase[ks * 4]);
#pragma unroll
        for (int nt = 0; nt < 4; ++nt) {
            short8 b = __builtin_bit_cast(short8, Bu[(((size_t)T * 4 + nt) * 8 + ks) * 64 + l]);
            acc[nt] = __builtin_amdgcn_mfma_f32_16x16x32_bf16(a, b, acc[nt], 0, 0, 0);
        }
    }

    // D: row = m0 + 4g + r, col = nt*16 + i  (m89-verified mapping)
#pragma unroll
    for (int nt = 0; nt < 4; ++nt) {
        int col = nt * 16 + i;
#pragma unroll
        for (int r = 0; r < 4; ++r) {
            int node = m0 + 4 * g + r;
            if (node < NN) {
                size_t idx = (size_t)node * DIM + col;
                float v = acc[nt][r];
                v = v > 0.f ? v : 0.f;
                float o = bf2f(xinb[idx]) + v;
                if (T < 3) xob[idx] = (unsigned short)bf16rne(o);
                else fout[idx] = o;
            }
        }
    }
}

// ---------------- Host ----------------

extern "C" void kernel_launch(void* const* d_in, const int* in_sizes, int n_in,
                              void* d_out, int out_size, void* d_ws, size_t ws_size,
                              hipStream_t stream) {
    const float* x       = (const float*)d_in[0];
    const float* W_edge  = (const float*)d_in[1];
    const float* b_edge  = (const float*)d_in[2];
    const float* nu_edge = (const float*)d_in[3];
    const float* W_t     = (const float*)d_in[4];
    const float* b_t     = (const float*)d_in[5];
    const float* nu_kt   = (const float*)d_in[6];
    const int* esrc = (const int*)d_in[7];
    const int* edst = (const int*)d_in[8];
    const int* ehop = (const int*)d_in[9];
    const int* etyp = (const int*)d_in[10];
    float* out = (float*)d_out;

    char* ws = (char*)d_ws;
    size_t off = 0;
    auto alloc = [&](size_t bytes) {
        void* p = ws + off;
        off = (off + bytes + 255) & ~(size_t)255;
        return p;
    };
    const size_t PLBZ = (size_t)(NN + 1) * DIM * 2;  // bf16 plane + zero row (ZROW)
    int* cnt  = (int*)alloc((size_t)NN * 4);         // per-node degree counter
    int* gcur = (int*)alloc(8 * 4);                  // per-range partition cursors
    uint2* pe = (uint2*)alloc((size_t)8 * RCAP * 8); // partitioned edges, 7.5 MB
    unsigned int* buf = (unsigned int*)alloc((size_t)NN * NDCAP * 4);   // 9.6 MB
    unsigned short* xb0 = (unsigned short*)alloc(PLBZ);  // bf16 layer planes (+zero row)
    unsigned short* pA  = (unsigned short*)alloc(PLBZ);
    unsigned short* pB  = (unsigned short*)alloc(PLBZ);
    unsigned short* aAll  = (unsigned short*)alloc((size_t)NN_PAD * 256 * 2);  // [node][256] bf16
    unsigned short* Bpack = (unsigned short*)alloc((size_t)4 * 4 * 8 * 512 * 2);
    unsigned short* G2A  = (unsigned short*)alloc(PLBZ); // rolling hop-sum planes (bf16)
    unsigned short* G2B  = (unsigned short*)alloc(PLBZ);
    unsigned short* G3A  = (unsigned short*)alloc(PLBZ);
    unsigned short* G3B  = (unsigned short*)alloc(PLBZ);
    unsigned short* G4   = (unsigned short*)alloc(PLBZ);
    (void)ws_size; (void)in_sizes; (void)n_in; (void)out_size;

    // Bucket build: PAD-prefill + partition (1 pass) -> XCD-affine scatter (1 pass)
    hipMemsetAsync(cnt, 0, (size_t)NN * 4 + 256, stream);   // cnt + gcur (adjacent)
    hipMemsetAsync(xb0 + (size_t)ZROW * DIM, 0, DIM * 2, stream);
    hipMemsetAsync(pA + (size_t)ZROW * DIM, 0, DIM * 2, stream);
    hipMemsetAsync(pB + (size_t)ZROW * DIM, 0, DIM * 2, stream);
    k_fill<<<(NN * NDCAP / 4 + 255) / 256, 256, 0, stream>>>((uint4*)buf);
    k_cvt<<<(NN * DIM / 4 + 255) / 256, 256, 0, stream>>>(x, xb0);
    k_pack<<<256, 256, 0, stream>>>(W_edge, W_t, Bpack);
    k_part<<<SC_SLICES, 256, 0, stream>>>(esrc, edst, etyp, ehop, gcur, pe);
    k_scatter<<<8 * ((RCAP + SC_CHUNK - 1) / SC_CHUNK), 256, 0, stream>>>(gcur, pe, cnt, buf);

    const int ga = (NN / 2 + 3) / 4;         // 2 nodes/wave, 4 waves/block -> 6250 blocks
    const int gm = NN_PAD / 64;              // 782 blocks, 64-node tile, 256 thr

    // t = 0: write G2[0],G3[0],G4[0]; no hop row (B hop slice = 0)
    k_agg<0><<<ga, 256, 0, stream>>>(cnt, buf, xb0, nu_edge, nu_kt,
                                     G4, G4, G4, aAll, G2A, G3A, G4);
    k_mm<0><<<gm, 256, 0, stream>>>(aAll, Bpack, b_edge, nu_edge, b_t, nu_kt,
                                    xb0, pA, nullptr);
    // t = 1: write G2[1],G3[1]; hop row = nk2*G2[0]
    k_agg<1><<<ga, 256, 0, stream>>>(cnt, buf, pA, nu_edge, nu_kt,
                                     G2A, G4, G4, aAll, G2B, G3B, G4);
    k_mm<1><<<gm, 256, 0, stream>>>(aAll, Bpack, b_edge, nu_edge, b_t, nu_kt,
                                    pA, pB, nullptr);
    // t = 2: write G2[2] (->G2A); hop row = nk2*G2[1] + nk3*G3[0]
    k_agg<2><<<ga, 256, 0, stream>>>(cnt, buf, pB, nu_edge, nu_kt,
                                     G2B, G3A, G4, aAll, G2A, G3A, G4);
    k_mm<2><<<gm, 256, 0, stream>>>(aAll, Bpack, b_edge, nu_edge, b_t, nu_kt,
                                    pB, pA, nullptr);
    // t = 3: no G writes; hop row = nk2*G2[2] + nk3*G3[1] + nk4*G4[0]; f32 out
    k_agg<3><<<ga, 256, 0, stream>>>(cnt, buf, pA, nu_edge, nu_kt,
                                     G2A, G3B, G4, aAll, G2B, G3B, G4);
    k_mm<3><<<gm, 256, 0, stream>>>(aAll, Bpack, b_edge, nu_edge, b_t, nu_kt,
                                    pA, nullptr, out);
}

// Round 25
// 223.132 us; speedup vs baseline: 1.0674x; 1.0674x over previous
//
#include <hip/hip_runtime.h>

#define NN 50000
#define NN_PAD 50048                    // 64-aligned, covers last k_mm tile
#define NE 800000
#define DIM 64
#define TL 4
#define ET 3
#define MH 6
#define NDCAP 64                        // per-node bucket capacity (deg ~Poisson(16))
#define SC_CHUNK 2048                   // edges per block slice
#define SC_SLICES ((NE + SC_CHUNK - 1) / SC_CHUNK)   // 391
#define RCAP 116384                     // per-range partition capacity (NE/8 + 16384)
#define ZROW NN                         // zero row index in bf16 planes
#define PAD_ENTRY ((unsigned)ZROW | 0x00300000u)   // srcn=ZROW (zeros), typ=3, hop=0
#define BUF_U4 (NN * NDCAP / 4)         // 800000
#define CNT_U4 ((NN + 8) * 4 / 16)      // 12502 (cnt + gcur, adjacent)

typedef __attribute__((ext_vector_type(8))) short short8;
typedef __attribute__((ext_vector_type(4))) float f32x4;
typedef __attribute__((ext_vector_type(2))) float f32x2;

__device__ __forceinline__ unsigned bf16rne(float f) {
    unsigned b = __float_as_uint(f);
    return (b + 0x7FFFu + ((b >> 16) & 1u)) >> 16;
}
__device__ __forceinline__ float bf2f(unsigned short u) {
    return __uint_as_float((unsigned)u << 16);
}
__device__ __forceinline__ float bf2f_lo(unsigned u) {
    return __uint_as_float(u << 16);
}
__device__ __forceinline__ float bf2f_hi(unsigned u) {
    return __uint_as_float(u & 0xFFFF0000u);
}
__device__ __forceinline__ f32x2 pkfma(float w, f32x2 v, f32x2 acc) {
    return __builtin_elementwise_fma((f32x2){w, w}, v, acc);  // v_pk_fma_f32
}

// ---------------- Phase A: partition edges by dst-range (one streaming pass) -------------

static __global__ __launch_bounds__(256) void k_part(
        const int* __restrict__ src, const int* __restrict__ dst,
        const int* __restrict__ typ, const int* __restrict__ hop,
        int* __restrict__ gcur, uint2* __restrict__ pe) {
    __shared__ int lcnt[8];
    __shared__ int lbase[8];
    if (threadIdx.x < 8) lcnt[threadIdx.x] = 0;
    __syncthreads();
    const int base = blockIdx.x * SC_CHUNK + threadIdx.x;
    int myr[8];
    int myrank[8];
    uint2 myw[8];
#pragma unroll
    for (int k = 0; k < 8; ++k) {
        int e = base + k * 256;
        myr[k] = -1;
        if (e < NE) {
            int d = dst[e];
            int r = d / (NN / 8);
            myr[k] = r;
            myrank[k] = atomicAdd(&lcnt[r], 1);
            myw[k] = make_uint2((unsigned)src[e] | ((unsigned)hop[e] << 16)
                                                | ((unsigned)typ[e] << 20),
                                (unsigned)d);
        }
    }
    __syncthreads();
    if (threadIdx.x < 8)
        lbase[threadIdx.x] = atomicAdd(&gcur[threadIdx.x], lcnt[threadIdx.x]);
    __syncthreads();
#pragma unroll
    for (int k = 0; k < 8; ++k) {
        if (myr[k] >= 0) {
            int r = myr[k];
            pe[(size_t)r * RCAP + lbase[r] + myrank[k]] = myw[k];
        }
    }
}

// ------- Fused init: buf PAD-prefill + cnt/gcur zero + plane zero-rows (one launch) ------

static __global__ __launch_bounds__(256) void k_fill(
        uint4* __restrict__ b, uint4* __restrict__ cntg,
        unsigned short* __restrict__ z0, unsigned short* __restrict__ z1,
        unsigned short* __restrict__ z2) {
    int i = blockIdx.x * 256 + threadIdx.x;
    if (i < BUF_U4) {
        b[i] = make_uint4(PAD_ENTRY, PAD_ENTRY, PAD_ENTRY, PAD_ENTRY);
    } else if (i < BUF_U4 + CNT_U4) {
        cntg[i - BUF_U4] = make_uint4(0, 0, 0, 0);
    } else {
        int j = i - (BUF_U4 + CNT_U4);            // 0..23: 3 planes x 8 uint4 (128 B row)
        if (j < 24) {
            unsigned short* p = (j < 8) ? z0 : (j < 16) ? z1 : z2;
            ((uint4*)(p + (size_t)ZROW * DIM))[j & 7] = make_uint4(0, 0, 0, 0);
        }
    }
}

// ---------------- Phase B: XCD-affine scatter, linear slots ----------------

static __global__ __launch_bounds__(256) void k_scatter(
        const int* __restrict__ gcur, const uint2* __restrict__ pe,
        int* __restrict__ cnt, unsigned int* __restrict__ buf) {
    const int r = blockIdx.x & 7;                 // XCD id under round-robin dispatch
    const int blk = blockIdx.x >> 3;
    const int n = gcur[r];
    const int i0 = blk * SC_CHUNK + threadIdx.x;
#pragma unroll
    for (int k = 0; k < 8; ++k) {
        int i = i0 + k * 256;
        if (i < n) {
            uint2 w = pe[(size_t)r * RCAP + i];
            int d = (int)w.y;
            int slot = atomicAdd(&cnt[d], 1);
            if (slot < NDCAP) buf[(size_t)d * NDCAP + slot] = w.x;
        }
    }
}

// ---------------- f32 -> bf16 plane convert (initial x only) ----------------

static __global__ void k_cvt(const float* __restrict__ in, unsigned short* __restrict__ out) {
    int i = blockIdx.x * blockDim.x + threadIdx.x;   // one float4 per thread
    if (i >= NN * DIM / 4) return;
    float4 v = ((const float4*)in)[i];
    uint2 p;
    p.x = bf16rne(v.x) | (bf16rne(v.y) << 16);
    p.y = bf16rne(v.z) | (bf16rne(v.w) << 16);
    ((uint2*)out)[i] = p;
}

// ---------------- W pre-pack, interleaved k-map: k = 4*dd + m --------------------------

static __global__ void k_pack(const float* __restrict__ W_edge, const float* __restrict__ W_t,
                              unsigned short* __restrict__ Bpack) {
    int idx = blockIdx.x * 256 + threadIdx.x;   // 65536 total
    if (idx >= 4 * 4 * 8 * 512) return;
    int j = idx & 7;
    int lane = (idx >> 3) & 63;
    int ks = (idx >> 9) & 7;
    int nt = (idx >> 12) & 3;
    int T = idx >> 14;
    int k = ks * 32 + 8 * (lane >> 4) + j;     // k within [0,256)
    int n = nt * 16 + (lane & 15);
    int m = k & 3, dd = k >> 2;
    float v;
    if (m < 3) v = W_edge[(((size_t)m * TL + T) * DIM + dd) * DIM + n];
    else if (T >= 1) v = W_t[((size_t)T * DIM + dd) * DIM + n];
    else v = 0.f;                               // T=0: hop slice contributes zero
    Bpack[idx] = (unsigned short)bf16rne(v);
}

// ---------------- Aggregation: TWO nodes per wave (half = node), no shuffles -------------
// R23-proven configuration: default launch bounds, 16 unconditional trips + dependent ladder.

template <int T>
static __global__ __launch_bounds__(256) void k_agg(
        const int* __restrict__ cnt, const unsigned int* __restrict__ buf,
        const unsigned short* __restrict__ xb,
        const float* __restrict__ nu_edge, const float* __restrict__ nu_kt,
        const unsigned short* __restrict__ gp2, const unsigned short* __restrict__ gp3,
        const unsigned short* __restrict__ gp4,
        unsigned short* __restrict__ aAll, unsigned short* __restrict__ g2,
        unsigned short* __restrict__ g3, unsigned short* __restrict__ g4) {
    int gw = (blockIdx.x * blockDim.x + threadIdx.x) >> 6;   // wave id
    int pairbase = gw * 2;
    if (pairbase >= NN) return;
    int lane = threadIdx.x & 63;
    const int half = lane >> 5;
    const int hl = lane & 31;            // dims 2hl, 2hl+1
    const int node = pairbase + half;    // NN even -> node < NN

    // independent loads: entry chunks (broadcast per half), cnt, G planes
    const uint4* __restrict__ eb4 = (const uint4*)(buf + (size_t)node * NDCAP);
    uint4 e0 = eb4[0];
    uint4 e1 = eb4[1];
    uint4 e2 = eb4[2];
    uint4 e3 = eb4[3];
    int myc = cnt[node];

    f32x2 hp = {0.f, 0.f};
    if (T >= 1) {
        const float nk2 = nu_kt[T * MH + 2];
        unsigned p2 = *(const unsigned*)(gp2 + (size_t)node * DIM + 2 * hl);
        hp = pkfma(nk2, (f32x2){bf2f_lo(p2), bf2f_hi(p2)}, hp);
        if (T >= 2) {
            const float nk3 = nu_kt[T * MH + 3];
            unsigned p3 = *(const unsigned*)(gp3 + (size_t)node * DIM + 2 * hl);
            hp = pkfma(nk3, (f32x2){bf2f_lo(p3), bf2f_hi(p3)}, hp);
        }
        if (T >= 3) {
            const float nk4 = nu_kt[T * MH + 4];
            unsigned p4 = *(const unsigned*)(gp4 + (size_t)node * DIM + 2 * hl);
            hp = pkfma(nk4, (f32x2){bf2f_lo(p4), bf2f_hi(p4)}, hp);
        }
    }

    int c0 = __builtin_amdgcn_readlane(myc, 0);
    int c1 = __builtin_amdgcn_readlane(myc, 32);
    const int ntmax = min(max(c0, c1), NDCAP);   // uniform trip count

    f32x2 st = {0.f, 0.f};
    f32x2 s1 = {0.f, 0.f};
    f32x2 s2 = {0.f, 0.f};
    f32x2 a2 = {0.f, 0.f};
    f32x2 a3 = {0.f, 0.f};
    f32x2 a4 = {0.f, 0.f};

#define TRIPE(E)                                                                 \
    {                                                                            \
        unsigned sp = (E);                                                       \
        int srcn = (int)(sp & 0xFFFFu);                                          \
        unsigned pk = *(const unsigned*)(xb + (size_t)srcn * DIM + 2 * hl);      \
        f32x2 v = {bf2f_lo(pk), bf2f_hi(pk)};                                    \
        st = st + v;                       /* unflagged: pads are zero */        \
        unsigned tf = (sp >> 20) & 3u;                                           \
        s1 = pkfma((tf == 1u) ? 1.f : 0.f, v, s1);                               \
        s2 = pkfma((tf == 2u) ? 1.f : 0.f, v, s2);                               \
        if (T <= 2) {                                                            \
            unsigned hf = (sp >> 16) & 15u;                                      \
            a2 = pkfma((hf == 2u) ? 1.f : 0.f, v, a2);                           \
            if (T <= 1) a3 = pkfma((hf == 3u) ? 1.f : 0.f, v, a3);               \
            if (T == 0) a4 = pkfma((hf == 4u) ? 1.f : 0.f, v, a4);               \
        }                                                                        \
    }

    // unconditional 16 trips (covers ntmax <= 16; pads harmless)
    TRIPE(e0.x) TRIPE(e0.y) TRIPE(e0.z) TRIPE(e0.w)
    TRIPE(e1.x) TRIPE(e1.y) TRIPE(e1.z) TRIPE(e1.w)
    TRIPE(e2.x) TRIPE(e2.y) TRIPE(e2.z) TRIPE(e2.w)
    TRIPE(e3.x) TRIPE(e3.y) TRIPE(e3.z) TRIPE(e3.w)
    if (ntmax > 16) {                    // 4-granular ladder (wave-uniform)
        uint4 e4 = eb4[4];
        TRIPE(e4.x) TRIPE(e4.y) TRIPE(e4.z) TRIPE(e4.w)
        if (ntmax > 20) {
            uint4 e5 = eb4[5];
            TRIPE(e5.x) TRIPE(e5.y) TRIPE(e5.z) TRIPE(e5.w)
            if (ntmax > 24) {
                uint4 e6 = eb4[6];
                TRIPE(e6.x) TRIPE(e6.y) TRIPE(e6.z) TRIPE(e6.w)
                if (ntmax > 28) {
                    uint4 e7 = eb4[7];
                    TRIPE(e7.x) TRIPE(e7.y) TRIPE(e7.z) TRIPE(e7.w)
                    if (ntmax > 32) {    // ~1e-4 of waves
                        for (int p = 32; p < ntmax; ++p)
                            TRIPE(buf[(size_t)node * NDCAP + p])
                    }
                }
            }
        }
    }
#undef TRIPE

    f32x2 s0 = st - s1 - s2;             // no cross-half reduction needed

    {
        float nu0 = nu_edge[0 * TL + T];
        float nu1 = nu_edge[1 * TL + T];
        float nu2 = nu_edge[2 * TL + T];
        uint4 pk;   // packed A row [node][d*4+m] for d = 2hl, 2hl+1
        pk.x = bf16rne(nu0 * s0.x) | (bf16rne(nu1 * s1.x) << 16);
        pk.y = bf16rne(nu2 * s2.x) | (bf16rne(hp.x) << 16);
        pk.z = bf16rne(nu0 * s0.y) | (bf16rne(nu1 * s1.y) << 16);
        pk.w = bf16rne(nu2 * s2.y) | (bf16rne(hp.y) << 16);
        *(uint4*)(aAll + (size_t)node * 256 + hl * 8) = pk;
        const size_t go = (size_t)node * DIM + 2 * hl;
        if (T <= 2) *(unsigned*)(g2 + go) = bf16rne(a2.x) | (bf16rne(a2.y) << 16);
        if (T <= 1) *(unsigned*)(g3 + go) = bf16rne(a3.x) | (bf16rne(a3.y) << 16);
        if (T == 0) *(unsigned*)(g4 + go) = bf16rne(a4.x) | (bf16rne(a4.y) << 16);
    }
}

// ---------------- Matmul via MFMA; bf16 residual chain; f32 out only at T=3 --------------

template <int T>
static __global__ __launch_bounds__(256) void k_mm(
        const unsigned short* __restrict__ aAll,
        const unsigned short* __restrict__ Bpack,
        const float* __restrict__ b_edge, const float* __restrict__ nu_edge,
        const float* __restrict__ b_t, const float* __restrict__ nu_kt,
        const unsigned short* __restrict__ xinb, unsigned short* __restrict__ xob,
        float* __restrict__ fout) {
    const int w = __builtin_amdgcn_readfirstlane(threadIdx.x >> 6);
    const int l = threadIdx.x & 63;
    const int g = l >> 4, i = l & 15;
    const int m0 = blockIdx.x * 64 + w * 16;

    const float nu0 = nu_edge[0 * TL + T], nu1 = nu_edge[1 * TL + T],
                nu2 = nu_edge[2 * TL + T];
    float nsum = 0.f;
    if (T >= 1) {
        nsum = nu_kt[T * MH + 2];
        if (T >= 2) nsum += nu_kt[T * MH + 3];
        if (T >= 3) nsum += nu_kt[T * MH + 4];
    }

    f32x4 acc[4];
#pragma unroll
    for (int nt = 0; nt < 4; ++nt) {
        int col = nt * 16 + i;
        float b = nu0 * b_edge[(0 * TL + T) * DIM + col]
                + nu1 * b_edge[(1 * TL + T) * DIM + col]
                + nu2 * b_edge[(2 * TL + T) * DIM + col];
        if (T >= 1) b = fmaf(nsum, b_t[T * DIM + col], b);
        acc[nt] = (f32x4){b, b, b, b};
    }

    // A: row = m0+i, k = ks*32 + 8g + [0..8)  -> one uint4 per k-step
    const uint4* __restrict__ Abase = (const uint4*)(aAll + (size_t)(m0 + i) * 256 + g * 8);
    const uint4* __restrict__ Bu = (const uint4*)Bpack;

#pragma unroll
    for (int ks = 0; ks < 8; ++ks) {
        short8 a = __builtin_bit_cast(short8, Abase[ks * 4]);
#pragma unroll
        for (int nt = 0; nt < 4; ++nt) {
            short8 b = __builtin_bit_cast(short8, Bu[(((size_t)T * 4 + nt) * 8 + ks) * 64 + l]);
            acc[nt] = __builtin_amdgcn_mfma_f32_16x16x32_bf16(a, b, acc[nt], 0, 0, 0);
        }
    }

    // D: row = m0 + 4g + r, col = nt*16 + i  (m89-verified mapping)
#pragma unroll
    for (int nt = 0; nt < 4; ++nt) {
        int col = nt * 16 + i;
#pragma unroll
        for (int r = 0; r < 4; ++r) {
            int node = m0 + 4 * g + r;
            if (node < NN) {
                size_t idx = (size_t)node * DIM + col;
                float v = acc[nt][r];
                v = v > 0.f ? v : 0.f;
                float o = bf2f(xinb[idx]) + v;
                if (T < 3) xob[idx] = (unsigned short)bf16rne(o);
                else fout[idx] = o;
            }
        }
    }
}

// ---------------- Host ----------------

extern "C" void kernel_launch(void* const* d_in, const int* in_sizes, int n_in,
                              void* d_out, int out_size, void* d_ws, size_t ws_size,
                              hipStream_t stream) {
    const float* x       = (const float*)d_in[0];
    const float* W_edge  = (const float*)d_in[1];
    const float* b_edge  = (const float*)d_in[2];
    const float* nu_edge = (const float*)d_in[3];
    const float* W_t     = (const float*)d_in[4];
    const float* b_t     = (const float*)d_in[5];
    const float* nu_kt   = (const float*)d_in[6];
    const int* esrc = (const int*)d_in[7];
    const int* edst = (const int*)d_in[8];
    const int* ehop = (const int*)d_in[9];
    const int* etyp = (const int*)d_in[10];
    float* out = (float*)d_out;

    char* ws = (char*)d_ws;
    size_t off = 0;
    auto alloc = [&](size_t bytes) {
        void* p = ws + off;
        off = (off + bytes + 255) & ~(size_t)255;
        return p;
    };
    const size_t PLBZ = (size_t)(NN + 1) * DIM * 2;  // bf16 plane + zero row (ZROW)
    int* cnt  = (int*)alloc((size_t)(NN + 8) * 4);   // per-node counters + gcur (adjacent)
    int* gcur = cnt + NN;
    uint2* pe = (uint2*)alloc((size_t)8 * RCAP * 8); // partitioned edges, 7.5 MB
    unsigned int* buf = (unsigned int*)alloc((size_t)NN * NDCAP * 4);   // 12.8 MB
    unsigned short* xb0 = (unsigned short*)alloc(PLBZ);  // bf16 layer planes (+zero row)
    unsigned short* pA  = (unsigned short*)alloc(PLBZ);
    unsigned short* pB  = (unsigned short*)alloc(PLBZ);
    unsigned short* aAll  = (unsigned short*)alloc((size_t)NN_PAD * 256 * 2);  // [node][256] bf16
    unsigned short* Bpack = (unsigned short*)alloc((size_t)4 * 4 * 8 * 512 * 2);
    unsigned short* G2A  = (unsigned short*)alloc(PLBZ); // rolling hop-sum planes (bf16)
    unsigned short* G2B  = (unsigned short*)alloc(PLBZ);
    unsigned short* G3A  = (unsigned short*)alloc(PLBZ);
    unsigned short* G3B  = (unsigned short*)alloc(PLBZ);
    unsigned short* G4   = (unsigned short*)alloc(PLBZ);
    (void)ws_size; (void)in_sizes; (void)n_in; (void)out_size;

    // Fused init (1 launch) -> cvt/pack -> partition (1 pass) -> XCD-affine scatter (1 pass)
    const int gfill = (BUF_U4 + CNT_U4 + 24 + 255) / 256;
    k_fill<<<gfill, 256, 0, stream>>>((uint4*)buf, (uint4*)cnt, xb0, pA, pB);
    k_cvt<<<(NN * DIM / 4 + 255) / 256, 256, 0, stream>>>(x, xb0);
    k_pack<<<256, 256, 0, stream>>>(W_edge, W_t, Bpack);
    k_part<<<SC_SLICES, 256, 0, stream>>>(esrc, edst, etyp, ehop, gcur, pe);
    k_scatter<<<8 * ((RCAP + SC_CHUNK - 1) / SC_CHUNK), 256, 0, stream>>>(gcur, pe, cnt, buf);

    const int ga = (NN / 2 + 3) / 4;         // 2 nodes/wave, 4 waves/block -> 6250 blocks
    const int gm = NN_PAD / 64;              // 782 blocks, 64-node tile, 256 thr

    // t = 0: write G2[0],G3[0],G4[0]; no hop row (B hop slice = 0)
    k_agg<0><<<ga, 256, 0, stream>>>(cnt, buf, xb0, nu_edge, nu_kt,
                                     G4, G4, G4, aAll, G2A, G3A, G4);
    k_mm<0><<<gm, 256, 0, stream>>>(aAll, Bpack, b_edge, nu_edge, b_t, nu_kt,
                                    xb0, pA, nullptr);
    // t = 1: write G2[1],G3[1]; hop row = nk2*G2[0]
    k_agg<1><<<ga, 256, 0, stream>>>(cnt, buf, pA, nu_edge, nu_kt,
                                     G2A, G4, G4, aAll, G2B, G3B, G4);
    k_mm<1><<<gm, 256, 0, stream>>>(aAll, Bpack, b_edge, nu_edge, b_t, nu_kt,
                                    pA, pB, nullptr);
    // t = 2: write G2[2] (->G2A); hop row = nk2*G2[1] + nk3*G3[0]
    k_agg<2><<<ga, 256, 0, stream>>>(cnt, buf, pB, nu_edge, nu_kt,
                                     G2B, G3A, G4, aAll, G2A, G3A, G4);
    k_mm<2><<<gm, 256, 0, stream>>>(aAll, Bpack, b_edge, nu_edge, b_t, nu_kt,
                                    pB, pA, nullptr);
    // t = 3: no G writes; hop row = nk2*G2[2] + nk3*G3[1] + nk4*G4[0]; f32 out
    k_agg<3><<<ga, 256, 0, stream>>>(cnt, buf, pA, nu_edge, nu_kt,
                                     G2A, G3B, G4, aAll, G2B, G3B, G4);
    k_mm<3><<<gm, 256, 0, stream>>>(aAll, Bpack, b_edge, nu_edge, b_t, nu_kt,
                                    pA, nullptr, out);
}

// Round 26
// 213.408 us; speedup vs baseline: 1.1160x; 1.0456x over previous
//
#include <hip/hip_runtime.h>

#define NN 50000
#define NN_PAD 50048                    // 64-aligned, covers last k_mm tile
#define NE 800000
#define DIM 64
#define TL 4
#define ET 3
#define MH 6
#define NDCAP 64                        // per-node bucket capacity (deg ~Poisson(16))
#define SC_CHUNK 2048                   // edges per block slice
#define SC_SLICES ((NE + SC_CHUNK - 1) / SC_CHUNK)   // 391
#define RCAP 116384                     // per-range partition capacity (NE/8 + 16384)
#define ZROW NN                         // zero row index in bf16 planes
#define PAD_ENTRY ((unsigned)ZROW | 0x00300000u)   // srcn=ZROW (zeros), typ=3, hop=0
#define BUF_U4 (NN * NDCAP / 4)         // 800000
#define CNT_U4 ((NN + 8) * 4 / 16)      // 12502 (cnt + gcur, adjacent)

typedef __attribute__((ext_vector_type(8))) short short8;
typedef __attribute__((ext_vector_type(4))) float f32x4;
typedef __attribute__((ext_vector_type(2))) float f32x2;

__device__ __forceinline__ unsigned bf16rne(float f) {
    unsigned b = __float_as_uint(f);
    return (b + 0x7FFFu + ((b >> 16) & 1u)) >> 16;
}
__device__ __forceinline__ float bf2f(unsigned short u) {
    return __uint_as_float((unsigned)u << 16);
}
__device__ __forceinline__ float bf2f_lo(unsigned u) {
    return __uint_as_float(u << 16);
}
__device__ __forceinline__ float bf2f_hi(unsigned u) {
    return __uint_as_float(u & 0xFFFF0000u);
}
__device__ __forceinline__ f32x4 pkfma4(float w, f32x4 v, f32x4 acc) {
    return __builtin_elementwise_fma((f32x4){w, w, w, w}, v, acc);  // 2x v_pk_fma_f32
}

// ---------------- Phase A: partition edges by dst-range (one streaming pass) -------------

static __global__ __launch_bounds__(256) void k_part(
        const int* __restrict__ src, const int* __restrict__ dst,
        const int* __restrict__ typ, const int* __restrict__ hop,
        int* __restrict__ gcur, uint2* __restrict__ pe) {
    __shared__ int lcnt[8];
    __shared__ int lbase[8];
    if (threadIdx.x < 8) lcnt[threadIdx.x] = 0;
    __syncthreads();
    const int base = blockIdx.x * SC_CHUNK + threadIdx.x;
    int myr[8];
    int myrank[8];
    uint2 myw[8];
#pragma unroll
    for (int k = 0; k < 8; ++k) {
        int e = base + k * 256;
        myr[k] = -1;
        if (e < NE) {
            int d = dst[e];
            int r = d / (NN / 8);
            myr[k] = r;
            myrank[k] = atomicAdd(&lcnt[r], 1);
            myw[k] = make_uint2((unsigned)src[e] | ((unsigned)hop[e] << 16)
                                                | ((unsigned)typ[e] << 20),
                                (unsigned)d);
        }
    }
    __syncthreads();
    if (threadIdx.x < 8)
        lbase[threadIdx.x] = atomicAdd(&gcur[threadIdx.x], lcnt[threadIdx.x]);
    __syncthreads();
#pragma unroll
    for (int k = 0; k < 8; ++k) {
        if (myr[k] >= 0) {
            int r = myr[k];
            pe[(size_t)r * RCAP + lbase[r] + myrank[k]] = myw[k];
        }
    }
}

// ------- Fused init: buf PAD-prefill + cnt/gcur zero + plane zero-rows (one launch) ------

static __global__ __launch_bounds__(256) void k_fill(
        uint4* __restrict__ b, uint4* __restrict__ cntg,
        unsigned short* __restrict__ z0, unsigned short* __restrict__ z1,
        unsigned short* __restrict__ z2) {
    int i = blockIdx.x * 256 + threadIdx.x;
    if (i < BUF_U4) {
        b[i] = make_uint4(PAD_ENTRY, PAD_ENTRY, PAD_ENTRY, PAD_ENTRY);
    } else if (i < BUF_U4 + CNT_U4) {
        cntg[i - BUF_U4] = make_uint4(0, 0, 0, 0);
    } else {
        int j = i - (BUF_U4 + CNT_U4);            // 0..23: 3 planes x 8 uint4 (128 B row)
        if (j < 24) {
            unsigned short* p = (j < 8) ? z0 : (j < 16) ? z1 : z2;
            ((uint4*)(p + (size_t)ZROW * DIM))[j & 7] = make_uint4(0, 0, 0, 0);
        }
    }
}

// ---------------- Phase B: XCD-affine scatter, linear slots ----------------

static __global__ __launch_bounds__(256) void k_scatter(
        const int* __restrict__ gcur, const uint2* __restrict__ pe,
        int* __restrict__ cnt, unsigned int* __restrict__ buf) {
    const int r = blockIdx.x & 7;                 // XCD id under round-robin dispatch
    const int blk = blockIdx.x >> 3;
    const int n = gcur[r];
    const int i0 = blk * SC_CHUNK + threadIdx.x;
#pragma unroll
    for (int k = 0; k < 8; ++k) {
        int i = i0 + k * 256;
        if (i < n) {
            uint2 w = pe[(size_t)r * RCAP + i];
            int d = (int)w.y;
            int slot = atomicAdd(&cnt[d], 1);
            if (slot < NDCAP) buf[(size_t)d * NDCAP + slot] = w.x;
        }
    }
}

// ---------------- f32 -> bf16 plane convert (initial x only) ----------------

static __global__ void k_cvt(const float* __restrict__ in, unsigned short* __restrict__ out) {
    int i = blockIdx.x * blockDim.x + threadIdx.x;   // one float4 per thread
    if (i >= NN * DIM / 4) return;
    float4 v = ((const float4*)in)[i];
    uint2 p;
    p.x = bf16rne(v.x) | (bf16rne(v.y) << 16);
    p.y = bf16rne(v.z) | (bf16rne(v.w) << 16);
    ((uint2*)out)[i] = p;
}

// ---------------- W pre-pack, interleaved k-map: k = 4*dd + m --------------------------

static __global__ void k_pack(const float* __restrict__ W_edge, const float* __restrict__ W_t,
                              unsigned short* __restrict__ Bpack) {
    int idx = blockIdx.x * 256 + threadIdx.x;   // 65536 total
    if (idx >= 4 * 4 * 8 * 512) return;
    int j = idx & 7;
    int lane = (idx >> 3) & 63;
    int ks = (idx >> 9) & 7;
    int nt = (idx >> 12) & 3;
    int T = idx >> 14;
    int k = ks * 32 + 8 * (lane >> 4) + j;     // k within [0,256)
    int n = nt * 16 + (lane & 15);
    int m = k & 3, dd = k >> 2;
    float v;
    if (m < 3) v = W_edge[(((size_t)m * TL + T) * DIM + dd) * DIM + n];
    else if (T >= 1) v = W_t[((size_t)T * DIM + dd) * DIM + n];
    else v = 0.f;                               // T=0: hop slice contributes zero
    Bpack[idx] = (unsigned short)bf16rne(v);
}

// ---------------- Aggregation: FOUR nodes per wave (quarter = node) ----------------------
// Quarter q (16 lanes) owns node 4w+q; lane ql covers dims 4ql..4ql+3 (uint2 gather, 8 B).
// One gather instruction serves 4 edges (4 x 128 B coalesced segments).
// Entries per-lane loaded -> no routing, no cross-lane reduction anywhere.

template <int T>
static __global__ __launch_bounds__(256) void k_agg(
        const int* __restrict__ cnt, const unsigned int* __restrict__ buf,
        const unsigned short* __restrict__ xb,
        const float* __restrict__ nu_edge, const float* __restrict__ nu_kt,
        const unsigned short* __restrict__ gp2, const unsigned short* __restrict__ gp3,
        const unsigned short* __restrict__ gp4,
        unsigned short* __restrict__ aAll, unsigned short* __restrict__ g2,
        unsigned short* __restrict__ g3, unsigned short* __restrict__ g4) {
    int gw = (blockIdx.x * blockDim.x + threadIdx.x) >> 6;   // wave id
    int quadbase = gw * 4;
    if (quadbase >= NN) return;
    int lane = threadIdx.x & 63;
    const int q = lane >> 4;             // quarter 0..3
    const int ql = lane & 15;            // dims 4ql..4ql+3
    const int node = quadbase + q;       // NN % 4 == 0 -> node < NN

    // independent loads: entry chunks (broadcast per quarter), cnt, G planes
    const uint4* __restrict__ eb4 = (const uint4*)(buf + (size_t)node * NDCAP);
    uint4 e0 = eb4[0];
    uint4 e1 = eb4[1];
    uint4 e2 = eb4[2];
    uint4 e3 = eb4[3];
    int myc = cnt[node];

    f32x4 hp = {0.f, 0.f, 0.f, 0.f};
    if (T >= 1) {
        const float nk2 = nu_kt[T * MH + 2];
        uint2 p2 = *(const uint2*)(gp2 + (size_t)node * DIM + 4 * ql);
        hp = pkfma4(nk2, (f32x4){bf2f_lo(p2.x), bf2f_hi(p2.x),
                                 bf2f_lo(p2.y), bf2f_hi(p2.y)}, hp);
        if (T >= 2) {
            const float nk3 = nu_kt[T * MH + 3];
            uint2 p3 = *(const uint2*)(gp3 + (size_t)node * DIM + 4 * ql);
            hp = pkfma4(nk3, (f32x4){bf2f_lo(p3.x), bf2f_hi(p3.x),
                                     bf2f_lo(p3.y), bf2f_hi(p3.y)}, hp);
        }
        if (T >= 3) {
            const float nk4 = nu_kt[T * MH + 4];
            uint2 p4 = *(const uint2*)(gp4 + (size_t)node * DIM + 4 * ql);
            hp = pkfma4(nk4, (f32x4){bf2f_lo(p4.x), bf2f_hi(p4.x),
                                     bf2f_lo(p4.y), bf2f_hi(p4.y)}, hp);
        }
    }

    int c0 = __builtin_amdgcn_readlane(myc, 0);
    int c1 = __builtin_amdgcn_readlane(myc, 16);
    int c2 = __builtin_amdgcn_readlane(myc, 32);
    int c3 = __builtin_amdgcn_readlane(myc, 48);
    const int ntmax = min(max(max(c0, c1), max(c2, c3)), NDCAP);   // uniform trip count

    f32x4 st = {0.f, 0.f, 0.f, 0.f};
    f32x4 s1 = {0.f, 0.f, 0.f, 0.f};
    f32x4 s2 = {0.f, 0.f, 0.f, 0.f};
    f32x4 a2 = {0.f, 0.f, 0.f, 0.f};
    f32x4 a3 = {0.f, 0.f, 0.f, 0.f};
    f32x4 a4 = {0.f, 0.f, 0.f, 0.f};

#define TRIPE(E)                                                                 \
    {                                                                            \
        unsigned sp = (E);                                                       \
        int srcn = (int)(sp & 0xFFFFu);                                          \
        uint2 pk = *(const uint2*)(xb + (size_t)srcn * DIM + 4 * ql);            \
        f32x4 v = {bf2f_lo(pk.x), bf2f_hi(pk.x), bf2f_lo(pk.y), bf2f_hi(pk.y)};  \
        st = st + v;                       /* unflagged: pads are zero */        \
        unsigned tf = (sp >> 20) & 3u;                                           \
        s1 = pkfma4((tf == 1u) ? 1.f : 0.f, v, s1);                              \
        s2 = pkfma4((tf == 2u) ? 1.f : 0.f, v, s2);                              \
        if (T <= 2) {                                                            \
            unsigned hf = (sp >> 16) & 15u;                                      \
            a2 = pkfma4((hf == 2u) ? 1.f : 0.f, v, a2);                          \
            if (T <= 1) a3 = pkfma4((hf == 3u) ? 1.f : 0.f, v, a3);              \
            if (T == 0) a4 = pkfma4((hf == 4u) ? 1.f : 0.f, v, a4);              \
        }                                                                        \
    }

    // unconditional 16 trips (covers ntmax <= 16; pads harmless)
    TRIPE(e0.x) TRIPE(e0.y) TRIPE(e0.z) TRIPE(e0.w)
    TRIPE(e1.x) TRIPE(e1.y) TRIPE(e1.z) TRIPE(e1.w)
    TRIPE(e2.x) TRIPE(e2.y) TRIPE(e2.z) TRIPE(e2.w)
    TRIPE(e3.x) TRIPE(e3.y) TRIPE(e3.z) TRIPE(e3.w)
    if (ntmax > 16) {                    // 4-granular ladder (wave-uniform)
        uint4 e4 = eb4[4];
        TRIPE(e4.x) TRIPE(e4.y) TRIPE(e4.z) TRIPE(e4.w)
        if (ntmax > 20) {
            uint4 e5 = eb4[5];
            TRIPE(e5.x) TRIPE(e5.y) TRIPE(e5.z) TRIPE(e5.w)
            if (ntmax > 24) {
                uint4 e6 = eb4[6];
                TRIPE(e6.x) TRIPE(e6.y) TRIPE(e6.z) TRIPE(e6.w)
                if (ntmax > 28) {
                    uint4 e7 = eb4[7];
                    TRIPE(e7.x) TRIPE(e7.y) TRIPE(e7.z) TRIPE(e7.w)
                    if (ntmax > 32) {    // ~1e-4 of waves
                        for (int p = 32; p < ntmax; ++p)
                            TRIPE(buf[(size_t)node * NDCAP + p])
                    }
                }
            }
        }
    }
#undef TRIPE

    f32x4 s0 = st - s1 - s2;             // no cross-lane reduction needed

    {
        float nu0 = nu_edge[0 * TL + T];
        float nu1 = nu_edge[1 * TL + T];
        float nu2 = nu_edge[2 * TL + T];
        // packed A row [node][d*4+m] for d = 4ql..4ql+3 -> 16 bf16 = 2 uint4
        uint4 w0, w1;
        w0.x = bf16rne(nu0 * s0.x) | (bf16rne(nu1 * s1.x) << 16);
        w0.y = bf16rne(nu2 * s2.x) | (bf16rne(hp.x) << 16);
        w0.z = bf16rne(nu0 * s0.y) | (bf16rne(nu1 * s1.y) << 16);
        w0.w = bf16rne(nu2 * s2.y) | (bf16rne(hp.y) << 16);
        w1.x = bf16rne(nu0 * s0.z) | (bf16rne(nu1 * s1.z) << 16);
        w1.y = bf16rne(nu2 * s2.z) | (bf16rne(hp.z) << 16);
        w1.z = bf16rne(nu0 * s0.w) | (bf16rne(nu1 * s1.w) << 16);
        w1.w = bf16rne(nu2 * s2.w) | (bf16rne(hp.w) << 16);
        uint4* A4 = (uint4*)(aAll + (size_t)node * 256 + ql * 16);
        A4[0] = w0;
        A4[1] = w1;
        const size_t go = (size_t)node * DIM + 4 * ql;
        if (T <= 2) {
            uint2 gv;
            gv.x = bf16rne(a2.x) | (bf16rne(a2.y) << 16);
            gv.y = bf16rne(a2.z) | (bf16rne(a2.w) << 16);
            *(uint2*)(g2 + go) = gv;
        }
        if (T <= 1) {
            uint2 gv;
            gv.x = bf16rne(a3.x) | (bf16rne(a3.y) << 16);
            gv.y = bf16rne(a3.z) | (bf16rne(a3.w) << 16);
            *(uint2*)(g3 + go) = gv;
        }
        if (T == 0) {
            uint2 gv;
            gv.x = bf16rne(a4.x) | (bf16rne(a4.y) << 16);
            gv.y = bf16rne(a4.z) | (bf16rne(a4.w) << 16);
            *(uint2*)(g4 + go) = gv;
        }
    }
}

// ---------------- Matmul via MFMA; bf16 residual chain; f32 out only at T=3 --------------

template <int T>
static __global__ __launch_bounds__(256) void k_mm(
        const unsigned short* __restrict__ aAll,
        const unsigned short* __restrict__ Bpack,
        const float* __restrict__ b_edge, const float* __restrict__ nu_edge,
        const float* __restrict__ b_t, const float* __restrict__ nu_kt,
        const unsigned short* __restrict__ xinb, unsigned short* __restrict__ xob,
        float* __restrict__ fout) {
    const int w = __builtin_amdgcn_readfirstlane(threadIdx.x >> 6);
    const int l = threadIdx.x & 63;
    const int g = l >> 4, i = l & 15;
    const int m0 = blockIdx.x * 64 + w * 16;

    const float nu0 = nu_edge[0 * TL + T], nu1 = nu_edge[1 * TL + T],
                nu2 = nu_edge[2 * TL + T];
    float nsum = 0.f;
    if (T >= 1) {
        nsum = nu_kt[T * MH + 2];
        if (T >= 2) nsum += nu_kt[T * MH + 3];
        if (T >= 3) nsum += nu_kt[T * MH + 4];
    }

    f32x4 acc[4];
#pragma unroll
    for (int nt = 0; nt < 4; ++nt) {
        int col = nt * 16 + i;
        float b = nu0 * b_edge[(0 * TL + T) * DIM + col]
                + nu1 * b_edge[(1 * TL + T) * DIM + col]
                + nu2 * b_edge[(2 * TL + T) * DIM + col];
        if (T >= 1) b = fmaf(nsum, b_t[T * DIM + col], b);
        acc[nt] = (f32x4){b, b, b, b};
    }

    // A: row = m0+i, k = ks*32 + 8g + [0..8)  -> one uint4 per k-step
    const uint4* __restrict__ Abase = (const uint4*)(aAll + (size_t)(m0 + i) * 256 + g * 8);
    const uint4* __restrict__ Bu = (const uint4*)Bpack;

#pragma unroll
    for (int ks = 0; ks < 8; ++ks) {
        short8 a = __builtin_bit_cast(short8, Abase[ks * 4]);
#pragma unroll
        for (int nt = 0; nt < 4; ++nt) {
            short8 b = __builtin_bit_cast(short8, Bu[(((size_t)T * 4 + nt) * 8 + ks) * 64 + l]);
            acc[nt] = __builtin_amdgcn_mfma_f32_16x16x32_bf16(a, b, acc[nt], 0, 0, 0);
        }
    }

    // D: row = m0 + 4g + r, col = nt*16 + i  (m89-verified mapping)
#pragma unroll
    for (int nt = 0; nt < 4; ++nt) {
        int col = nt * 16 + i;
#pragma unroll
        for (int r = 0; r < 4; ++r) {
            int node = m0 + 4 * g + r;
            if (node < NN) {
                size_t idx = (size_t)node * DIM + col;
                float v = acc[nt][r];
                v = v > 0.f ? v : 0.f;
                float o = bf2f(xinb[idx]) + v;
                if (T < 3) xob[idx] = (unsigned short)bf16rne(o);
                else fout[idx] = o;
            }
        }
    }
}

// ---------------- Host ----------------

extern "C" void kernel_launch(void* const* d_in, const int* in_sizes, int n_in,
                              void* d_out, int out_size, void* d_ws, size_t ws_size,
                              hipStream_t stream) {
    const float* x       = (const float*)d_in[0];
    const float* W_edge  = (const float*)d_in[1];
    const float* b_edge  = (const float*)d_in[2];
    const float* nu_edge = (const float*)d_in[3];
    const float* W_t     = (const float*)d_in[4];
    const float* b_t     = (const float*)d_in[5];
    const float* nu_kt   = (const float*)d_in[6];
    const int* esrc = (const int*)d_in[7];
    const int* edst = (const int*)d_in[8];
    const int* ehop = (const int*)d_in[9];
    const int* etyp = (const int*)d_in[10];
    float* out = (float*)d_out;

    char* ws = (char*)d_ws;
    size_t off = 0;
    auto alloc = [&](size_t bytes) {
        void* p = ws + off;
        off = (off + bytes + 255) & ~(size_t)255;
        return p;
    };
    const size_t PLBZ = (size_t)(NN + 1) * DIM * 2;  // bf16 plane + zero row (ZROW)
    int* cnt  = (int*)alloc((size_t)(NN + 8) * 4);   // per-node counters + gcur (adjacent)
    int* gcur = cnt + NN;
    uint2* pe = (uint2*)alloc((size_t)8 * RCAP * 8); // partitioned edges, 7.5 MB
    unsigned int* buf = (unsigned int*)alloc((size_t)NN * NDCAP * 4);   // 12.8 MB
    unsigned short* xb0 = (unsigned short*)alloc(PLBZ);  // bf16 layer planes (+zero row)
    unsigned short* pA  = (unsigned short*)alloc(PLBZ);
    unsigned short* pB  = (unsigned short*)alloc(PLBZ);
    unsigned short* aAll  = (unsigned short*)alloc((size_t)NN_PAD * 256 * 2);  // [node][256] bf16
    unsigned short* Bpack = (unsigned short*)alloc((size_t)4 * 4 * 8 * 512 * 2);
    unsigned short* G2A  = (unsigned short*)alloc(PLBZ); // rolling hop-sum planes (bf16)
    unsigned short* G2B  = (unsigned short*)alloc(PLBZ);
    unsigned short* G3A  = (unsigned short*)alloc(PLBZ);
    unsigned short* G3B  = (unsigned short*)alloc(PLBZ);
    unsigned short* G4   = (unsigned short*)alloc(PLBZ);
    (void)ws_size; (void)in_sizes; (void)n_in; (void)out_size;

    // Fused init (1 launch) -> cvt/pack -> partition (1 pass) -> XCD-affine scatter (1 pass)
    const int gfill = (BUF_U4 + CNT_U4 + 24 + 255) / 256;
    k_fill<<<gfill, 256, 0, stream>>>((uint4*)buf, (uint4*)cnt, xb0, pA, pB);
    k_cvt<<<(NN * DIM / 4 + 255) / 256, 256, 0, stream>>>(x, xb0);
    k_pack<<<256, 256, 0, stream>>>(W_edge, W_t, Bpack);
    k_part<<<SC_SLICES, 256, 0, stream>>>(esrc, edst, etyp, ehop, gcur, pe);
    k_scatter<<<8 * ((RCAP + SC_CHUNK - 1) / SC_CHUNK), 256, 0, stream>>>(gcur, pe, cnt, buf);

    const int ga = (NN / 4 + 3) / 4;         // 4 nodes/wave, 4 waves/block -> 3125 blocks
    const int gm = NN_PAD / 64;              // 782 blocks, 64-node tile, 256 thr

    // t = 0: write G2[0],G3[0],G4[0]; no hop row (B hop slice = 0)
    k_agg<0><<<ga, 256, 0, stream>>>(cnt, buf, xb0, nu_edge, nu_kt,
                                     G4, G4, G4, aAll, G2A, G3A, G4);
    k_mm<0><<<gm, 256, 0, stream>>>(aAll, Bpack, b_edge, nu_edge, b_t, nu_kt,
                                    xb0, pA, nullptr);
    // t = 1: write G2[1],G3[1]; hop row = nk2*G2[0]
    k_agg<1><<<ga, 256, 0, stream>>>(cnt, buf, pA, nu_edge, nu_kt,
                                     G2A, G4, G4, aAll, G2B, G3B, G4);
    k_mm<1><<<gm, 256, 0, stream>>>(aAll, Bpack, b_edge, nu_edge, b_t, nu_kt,
                                    pA, pB, nullptr);
    // t = 2: write G2[2] (->G2A); hop row = nk2*G2[1] + nk3*G3[0]
    k_agg<2><<<ga, 256, 0, stream>>>(cnt, buf, pB, nu_edge, nu_kt,
                                     G2B, G3A, G4, aAll, G2A, G3A, G4);
    k_mm<2><<<gm, 256, 0, stream>>>(aAll, Bpack, b_edge, nu_edge, b_t, nu_kt,
                                    pB, pA, nullptr);
    // t = 3: no G writes; hop row = nk2*G2[2] + nk3*G3[1] + nk4*G4[0]; f32 out
    k_agg<3><<<ga, 256, 0, stream>>>(cnt, buf, pA, nu_edge, nu_kt,
                                     G2A, G3B, G4, aAll, G2B, G3B, G4);
    k_mm<3><<<gm, 256, 0, stream>>>(aAll, Bpack, b_edge, nu_edge, b_t, nu_kt,
                                    pA, nullptr, out);
}